// Round 3
// baseline (75.700 us; speedup 1.0000x reference)
//
#include <hip/hip_runtime.h>
#include <hip/hip_bf16.h>

typedef unsigned short u16;
typedef unsigned int u32;
typedef float f32x4 __attribute__((ext_vector_type(4)));
typedef short s16x8 __attribute__((ext_vector_type(8)));

#define MFMA16(a,b,c) __builtin_amdgcn_mfma_f32_16x16x32_bf16((a),(b),(c),0,0,0)

static __device__ __forceinline__ u16 f2bf(float x){
  union { __hip_bfloat16 b; u16 u; } c;
  c.b = __float2bfloat16(x);
  return c.u;
}

// ---------------------------------------------------------------------------
// prep: build bf16 transposed/permuted weight buffers + gin[:, 0:512]
// ---------------------------------------------------------------------------
__global__ void prep_kernel(const float* __restrict__ Wm1, const float* __restrict__ Wm2,
                            const float* __restrict__ Wm3, const float* __restrict__ Wg1,
                            const float* __restrict__ Wr,  const float* __restrict__ Wt1,
                            const float* __restrict__ node,const float* __restrict__ prev,
                            const float* __restrict__ edge,const float* __restrict__ graph,
                            u16* __restrict__ WbT, u16* __restrict__ WgrT,
                            u16* __restrict__ Wm2T, u16* __restrict__ Wm3T,
                            u16* __restrict__ gin)
{
  int idx = blockIdx.x * 256 + threadIdx.x;
  if (idx < 147456) {                       // WbT: 288*512
    int n = idx >> 9, k = idx & 511;
    int part = k >> 7, kk = k & 127;
    float v = 0.f;
    if (n < 128) {                          // u = z@W_zi + gb@W_g
      if (part == 0)      v = Wm1[kk*128 + n];
      else if (part == 1) v = Wm1[(128+kk)*128 + n];
      else if (part == 3) v = Wm1[(640+kk)*128 + n];
    } else if (n < 256) {                   // v = z@W_zj + edge@W_e
      int nn = n - 128;
      if (part == 0)      v = Wm1[(256+kk)*128 + nn];
      else if (part == 1) v = Wm1[(384+kk)*128 + nn];
      else if (part == 2) v = Wm1[(512+kk)*128 + nn];
    } else if (n < 280) {                   // a_j(8) a_k(8) c(8)
      int tt = n - 256;
      if (tt < 8)       { if (part == 0) v = Wt1[kk*8 + tt]; }
      else if (tt < 16) { if (part == 0) v = Wt1[(128+kk)*8 + (tt-8)]; }
      else {
        int t = tt - 16;
        if (part == 0)      v = Wt1[(256+kk)*8 + t];
        else if (part == 2) v = Wt1[(384+kk)*8 + t] + Wt1[(512+kk)*8 + t] + Wt1[(640+kk)*8 + t];
        else if (part == 3) v = Wt1[(768+kk)*8 + t];
      }
    }
    WbT[idx] = f2bf(v);
    return;
  }
  idx -= 147456;
  if (idx < 163840) {                       // WgrT: 256*640
    int n = idx / 640, k = idx - n*640;
    int part = k >> 7, kk = k & 127;
    float v = 0.f;
    if (n < 128) {
      int r = (part==0) ? kk : (part==1) ? (128+kk) : (part==2) ? (384+kk)
                        : (part==3) ? (512+kk) : (256+kk);
      v = Wg1[r*128 + n];
    } else {
      int nn = n - 128;
      if (part == 0)      v = Wr[kk*128 + nn];
      else if (part == 1) v = Wr[(128+kk)*128 + nn];
      else if (part == 4) v = Wr[(256+kk)*128 + nn];
    }
    WgrT[idx] = f2bf(v);
    return;
  }
  idx -= 163840;
  if (idx < 16384) { int n = idx >> 7, k = idx & 127; Wm2T[idx] = f2bf(Wm2[k*128 + n]); return; }
  idx -= 16384;
  if (idx < 16384) { int n = idx >> 7, k = idx & 127; Wm3T[idx] = f2bf(Wm3[k*128 + n]); return; }
  idx -= 16384;
  {                                         // gin cols 0:512
    int row = idx >> 9, k = idx & 511;
    int part = k >> 7, kk = k & 127;
    float v;
    if (part == 0)      v = node[row*128 + kk];
    else if (part == 1) v = prev[row*128 + kk];
    else if (part == 2) v = edge[row*128 + kk];
    else                v = graph[(row >> 8)*128 + kk];
    gin[row*640 + k] = f2bf(v);
  }
}

// ---------------------------------------------------------------------------
// G1: uvt[1024][288] = gin[:,0:512] @ WbT^T
// ---------------------------------------------------------------------------
__global__ void gemm_uvt_kernel(const u16* __restrict__ gin, const u16* __restrict__ WbT,
                                float* __restrict__ uvt)
{
  int m0 = blockIdx.x * 16, n0 = blockIdx.y * 16;
  int lane = threadIdx.x;
  int lrow = lane & 15, lgrp = lane >> 4;
  const u16* arow = gin + (size_t)(m0 + lrow) * 640;
  const u16* brow = WbT + (size_t)(n0 + lrow) * 512;
  f32x4 acc = {0.f, 0.f, 0.f, 0.f};
#pragma unroll
  for (int k0 = 0; k0 < 16; ++k0) {
    s16x8 a = *reinterpret_cast<const s16x8*>(arow + k0*32 + lgrp*8);
    s16x8 b = *reinterpret_cast<const s16x8*>(brow + k0*32 + lgrp*8);
    acc = MFMA16(a, b, acc);
  }
#pragma unroll
  for (int r = 0; r < 4; ++r)
    uvt[(size_t)(m0 + lgrp*4 + r) * 288 + n0 + lrow] = acc[r];
}

// ---------------------------------------------------------------------------
// per-batch max over i of a_j, a_k
// ---------------------------------------------------------------------------
__global__ void maxat_kernel(const float* __restrict__ uvt, float* __restrict__ mjk)
{
  int b = blockIdx.x;
  int tid = threadIdx.x;
  int row = b*256 + tid;
  __shared__ float part[4][16];
  float v[16];
#pragma unroll
  for (int t = 0; t < 16; ++t) v[t] = uvt[(size_t)row*288 + 256 + t];
#pragma unroll
  for (int off = 32; off >= 1; off >>= 1) {
#pragma unroll
    for (int t = 0; t < 16; ++t) v[t] = fmaxf(v[t], __shfl_xor(v[t], off));
  }
  int wid = tid >> 6;
  if ((tid & 63) == 0) {
#pragma unroll
    for (int t = 0; t < 16; ++t) part[wid][t] = v[t];
  }
  __syncthreads();
  if (tid < 16)
    mjk[b*16 + tid] = fmaxf(fmaxf(part[0][tid], part[1][tid]),
                            fmaxf(part[2][tid], part[3][tid]));
}

// ---------------------------------------------------------------------------
// msgmax v3: swapped GEMMs, shared a1 k-slices, single barrier per 32-j block
// via double-buffered a1s/h2s software pipeline; a1s rows padded to 40 u16
// (20-dword stride -> 2-way banks, free). Block = one (b,i), 4 waves.
// Region(it): build a1(it+1) | barrier | GEMM2(it)+max | GEMM1(it+1)->h2(it+1)
// ---------------------------------------------------------------------------
__global__ __launch_bounds__(256, 4) void msgmax_kernel(const float* __restrict__ uvt,
    const u16* __restrict__ Wm2T, const u16* __restrict__ Wm3T,
    const float* __restrict__ bm1, const float* __restrict__ bm2,
    const float* __restrict__ bm3, u16* __restrict__ gin)
{
  const int row = blockIdx.x;
  const int b   = row >> 8;
  const int tid = threadIdx.x;
  const int w   = tid >> 6;
  const int lane = tid & 63;
  const int c = lane & 15, g = lane >> 4;

  __shared__ u16 a1s[2][2][4][16][40];  // [buf][jhalf][k0][j(c)][32 used + 8 pad]
  __shared__ u16 h2s[2][2][16][136];    // [buf][jhalf][j(c)][128 + 8 pad]

  // persistent weight A-fragments (swapped GEMM): rows = output cols
  s16x8 wb2[4][2], wb3[4][2];
#pragma unroll
  for (int mt = 0; mt < 2; ++mt) {
    int col = w*32 + mt*16 + c;
#pragma unroll
    for (int k0 = 0; k0 < 4; ++k0) {
      wb2[k0][mt] = *reinterpret_cast<const s16x8*>(Wm2T + col*128 + k0*32 + g*8);
      wb3[k0][mt] = *reinterpret_cast<const s16x8*>(Wm3T + col*128 + k0*32 + g*8);
    }
  }
  float4 bm2v[2];
#pragma unroll
  for (int mt = 0; mt < 2; ++mt)
    bm2v[mt] = *reinterpret_cast<const float4*>(bm2 + w*32 + mt*16 + 4*g);

  // u slice (k0 == w only), +bm1
  const float* urow = uvt + (size_t)row * 288;
  float uf[8];
  {
    int off = w*32 + g*8;
    float4 x = *reinterpret_cast<const float4*>(urow + off);
    float4 y = *reinterpret_cast<const float4*>(urow + off + 4);
    float4 p = *reinterpret_cast<const float4*>(bm1 + off);
    float4 q = *reinterpret_cast<const float4*>(bm1 + off + 4);
    uf[0]=x.x+p.x; uf[1]=x.y+p.y; uf[2]=x.z+p.z; uf[3]=x.w+p.w;
    uf[4]=y.x+q.x; uf[5]=y.y+q.y; uf[6]=y.z+q.z; uf[7]=y.w+q.w;
  }

  const float* vb = uvt + (size_t)(b*256) * 288 + 128;
  f32x4 mmax[2];
#pragma unroll
  for (int mt = 0; mt < 2; ++mt)
#pragma unroll
    for (int r = 0; r < 4; ++r) mmax[mt][r] = -1e30f;

  float4 vc[2][2];   // v slices for the next j-block: [jhalf][lo/hi]
#define LOADV(IT) do { \
  _Pragma("unroll") \
  for (int t = 0; t < 2; ++t) { \
    const float* p_ = vb + (size_t)((IT)*32 + t*16 + c) * 288 + w*32 + g*8; \
    vc[t][0] = *reinterpret_cast<const float4*>(p_); \
    vc[t][1] = *reinterpret_cast<const float4*>(p_ + 4); } } while (0)

  // build own a1 k-slice (k0 == w) for both j-halves from vc, into buffer BUF
#define A1W(BUF) do { \
  _Pragma("unroll") \
  for (int t = 0; t < 2; ++t) { \
    u32 d0 = (u32)f2bf(fmaxf(uf[0] + vc[t][0].x, 0.f)) \
           | ((u32)f2bf(fmaxf(uf[1] + vc[t][0].y, 0.f)) << 16); \
    u32 d1 = (u32)f2bf(fmaxf(uf[2] + vc[t][0].z, 0.f)) \
           | ((u32)f2bf(fmaxf(uf[3] + vc[t][0].w, 0.f)) << 16); \
    u32 d2 = (u32)f2bf(fmaxf(uf[4] + vc[t][1].x, 0.f)) \
           | ((u32)f2bf(fmaxf(uf[5] + vc[t][1].y, 0.f)) << 16); \
    u32 d3 = (u32)f2bf(fmaxf(uf[6] + vc[t][1].z, 0.f)) \
           | ((u32)f2bf(fmaxf(uf[7] + vc[t][1].w, 0.f)) << 16); \
    uint4 pk = {d0, d1, d2, d3}; \
    *reinterpret_cast<uint4*>(&a1s[BUF][t][w][c][g*8]) = pk; } } while (0)

  // GEMM1: h2(AB buf) = relu(Wm2^T . a1(AB)) + bm2 -> h2s[HB]
#define GEMM1(AB, HB) do { \
  f32x4 acc1[2][2] = {{{0,0,0,0},{0,0,0,0}},{{0,0,0,0},{0,0,0,0}}}; \
  _Pragma("unroll") \
  for (int t = 0; t < 2; ++t) \
    _Pragma("unroll") \
    for (int k0 = 0; k0 < 4; ++k0) { \
      s16x8 af = *reinterpret_cast<const s16x8*>(&a1s[AB][t][k0][c][g*8]); \
      acc1[t][0] = MFMA16(wb2[k0][0], af, acc1[t][0]); \
      acc1[t][1] = MFMA16(wb2[k0][1], af, acc1[t][1]); \
    } \
  _Pragma("unroll") \
  for (int t = 0; t < 2; ++t) \
    _Pragma("unroll") \
    for (int mt = 0; mt < 2; ++mt) { \
      u32 lo = (u32)f2bf(fmaxf(acc1[t][mt][0] + bm2v[mt].x, 0.f)) \
             | ((u32)f2bf(fmaxf(acc1[t][mt][1] + bm2v[mt].y, 0.f)) << 16); \
      u32 hi = (u32)f2bf(fmaxf(acc1[t][mt][2] + bm2v[mt].z, 0.f)) \
             | ((u32)f2bf(fmaxf(acc1[t][mt][3] + bm2v[mt].w, 0.f)) << 16); \
      uint2 pk = {lo, hi}; \
      *reinterpret_cast<uint2*>(&h2s[HB][t][c][w*32 + mt*16 + 4*g]) = pk; } } while (0)

  // GEMM2: msgs^T from h2s[HB], fold into running max
#define GEMM2(HB) do { \
  f32x4 acc2[2][2] = {{{0,0,0,0},{0,0,0,0}},{{0,0,0,0},{0,0,0,0}}}; \
  _Pragma("unroll") \
  for (int t = 0; t < 2; ++t) \
    _Pragma("unroll") \
    for (int k0 = 0; k0 < 4; ++k0) { \
      s16x8 a2 = *reinterpret_cast<const s16x8*>(&h2s[HB][t][c][k0*32 + g*8]); \
      acc2[t][0] = MFMA16(wb3[k0][0], a2, acc2[t][0]); \
      acc2[t][1] = MFMA16(wb3[k0][1], a2, acc2[t][1]); \
    } \
  _Pragma("unroll") \
  for (int mt = 0; mt < 2; ++mt) \
    _Pragma("unroll") \
    for (int r = 0; r < 4; ++r) \
      mmax[mt][r] = fmaxf(mmax[mt][r], fmaxf(acc2[0][mt][r], acc2[1][mt][r])); } while (0)

  // prologue: a1(block 0) -> buf 0; GEMM1(block 0) -> h2 buf 0
  LOADV(0);
  A1W(0);
  LOADV(1);
  __syncthreads();
  GEMM1(0, 0);

  for (int it = 0; it < 8; ++it) {
    int nb = (it + 1) & 1;
    if (it < 7) {
      A1W(nb);                 // vc holds v(it+1)
      if (it < 6) LOADV(it + 2);
    }
    __syncthreads();           // a1(it+1) and h2(it) now visible block-wide
    GEMM2(it & 1);
    if (it < 7) GEMM1(nb, nb);
  }
#undef LOADV
#undef A1W
#undef GEMM1
#undef GEMM2

  // reduce over the 16 j-lanes (c bits), fold bm3, packed global write
#pragma unroll
  for (int mt = 0; mt < 2; ++mt) {
    f32x4 m = mmax[mt];
#pragma unroll
    for (int off = 1; off < 16; off <<= 1) {
      m[0] = fmaxf(m[0], __shfl_xor(m[0], off));
      m[1] = fmaxf(m[1], __shfl_xor(m[1], off));
      m[2] = fmaxf(m[2], __shfl_xor(m[2], off));
      m[3] = fmaxf(m[3], __shfl_xor(m[3], off));
    }
    if (c == 0) {
      int col = w*32 + mt*16 + 4*g;
      u32 lo = (u32)f2bf(m[0] + bm3[col])   | ((u32)f2bf(m[1] + bm3[col+1]) << 16);
      u32 hi = (u32)f2bf(m[2] + bm3[col+2]) | ((u32)f2bf(m[3] + bm3[col+3]) << 16);
      uint2 pk = {lo, hi};
      *reinterpret_cast<uint2*>(gin + (size_t)row*640 + 512 + col) = pk;
    }
  }
}

// ---------------------------------------------------------------------------
// G2: [r1 | h_i] = gin(K=640) @ WgrT^T
// ---------------------------------------------------------------------------
__global__ void gemm_gate_kernel(const u16* __restrict__ gin, const u16* __restrict__ WgrT,
                                 const float* __restrict__ bg1, const float* __restrict__ br,
                                 float* __restrict__ r1, float* __restrict__ hi)
{
  int m0 = blockIdx.x * 16, n0 = blockIdx.y * 16;
  int lane = threadIdx.x;
  int lrow = lane & 15, lgrp = lane >> 4;
  const u16* arow = gin  + (size_t)(m0 + lrow) * 640;
  const u16* brow = WgrT + (size_t)(n0 + lrow) * 640;
  f32x4 acc = {0.f, 0.f, 0.f, 0.f};
#pragma unroll
  for (int k0 = 0; k0 < 20; ++k0) {
    s16x8 a = *reinterpret_cast<const s16x8*>(arow + k0*32 + lgrp*8);
    s16x8 b = *reinterpret_cast<const s16x8*>(brow + k0*32 + lgrp*8);
    acc = MFMA16(a, b, acc);
  }
  int col = n0 + lrow;
  float bv = (col < 128) ? bg1[col] : br[col - 128];
#pragma unroll
  for (int r = 0; r < 4; ++r) {
    int gr = m0 + lgrp*4 + r;
    if (col < 128) r1[gr*128 + col] = fmaxf(acc[r] + bv, 0.f);
    else           hi[gr*128 + col - 128] = acc[r] + bv;
  }
}

// ---------------------------------------------------------------------------
// finalize
// ---------------------------------------------------------------------------
__global__ void finalize_kernel(const float* __restrict__ r1, const float* __restrict__ hi,
                                const float* __restrict__ prev, const float* __restrict__ uvt,
                                const float* __restrict__ mjk,
                                const float* __restrict__ Wg2, const float* __restrict__ bg2,
                                const float* __restrict__ bt1, const float* __restrict__ Wt2,
                                const float* __restrict__ bt2, const float* __restrict__ gamma,
                                const float* __restrict__ beta, float* __restrict__ out)
{
  int row = blockIdx.x;
  int h = threadIdx.x;
  int b = row >> 8;
  __shared__ float r1s[128];
  __shared__ float red[4];
  r1s[h] = r1[row*128 + h];
  __syncthreads();
  float glin = bg2[h];
#pragma unroll 8
  for (int k = 0; k < 128; ++k) glin += r1s[k] * Wg2[k*128 + h];
  float g = 1.f / (1.f + __expf(-glin));
  float hg = g * hi[row*128 + h] + (1.f - g) * prev[row*128 + h];

  float s1 = hg, s2 = hg*hg;
#pragma unroll
  for (int off = 1; off < 64; off <<= 1) {
    s1 += __shfl_xor(s1, off);
    s2 += __shfl_xor(s2, off);
  }
  int wid = h >> 6;
  if ((h & 63) == 0) { red[wid] = s1; red[2 + wid] = s2; }
  __syncthreads();
  float mu  = (red[0] + red[1]) * 0.0078125f;
  float ex2 = (red[2] + red[3]) * 0.0078125f;
  float var = ex2 - mu*mu;
  float hn = (hg - mu) * rsqrtf(var + 1e-5f) * gamma[h] + beta[h];
  out[row*128 + h] = hn;

  float o2 = bt2[h];
#pragma unroll
  for (int t = 0; t < 8; ++t) {
    float tv = uvt[(size_t)row*288 + 272 + t] + bt1[t] + mjk[b*16 + t] + mjk[b*16 + 8 + t];
    tv = fmaxf(tv, 0.f);
    o2 += tv * Wt2[t*128 + h];
  }
  out[131072 + row*128 + h] = o2;
}

// ---------------------------------------------------------------------------
extern "C" void kernel_launch(void* const* d_in, const int* in_sizes, int n_in,
                              void* d_out, int out_size, void* d_ws, size_t ws_size,
                              hipStream_t stream) {
  const float* node  = (const float*)d_in[0];
  const float* edge  = (const float*)d_in[1];
  const float* graph = (const float*)d_in[2];
  const float* prev  = (const float*)d_in[3];
  const float* Wm1 = (const float*)d_in[4];
  const float* bm1 = (const float*)d_in[5];
  const float* Wm2 = (const float*)d_in[6];
  const float* bm2 = (const float*)d_in[7];
  const float* Wm3 = (const float*)d_in[8];
  const float* bm3 = (const float*)d_in[9];
  const float* Wg1 = (const float*)d_in[10];
  const float* bg1 = (const float*)d_in[11];
  const float* Wg2 = (const float*)d_in[12];
  const float* bg2 = (const float*)d_in[13];
  const float* Wr  = (const float*)d_in[14];
  const float* br  = (const float*)d_in[15];
  const float* Wt1 = (const float*)d_in[16];
  const float* bt1 = (const float*)d_in[17];
  const float* Wt2 = (const float*)d_in[18];
  const float* bt2 = (const float*)d_in[19];
  const float* gamma = (const float*)d_in[20];
  const float* beta  = (const float*)d_in[21];
  float* out = (float*)d_out;

  char* ws = (char*)d_ws;
  u16*   WbT  = (u16*)(ws + 0);        // 288*512*2   = 294912
  u16*   WgrT = (u16*)(ws + 294912);   // 256*640*2   = 327680
  u16*   Wm2T = (u16*)(ws + 622592);   // 16384*2
  u16*   Wm3T = (u16*)(ws + 655360);   // 16384*2
  u16*   gin  = (u16*)(ws + 688128);   // 1024*640*2  = 1310720
  float* uvt  = (float*)(ws + 1998848);// 1024*288*4  = 1179648
  float* r1   = (float*)(ws + 3178496);// 1024*128*4  = 524288
  float* hi   = (float*)(ws + 3702784);// 524288
  float* mjk  = (float*)(ws + 4227072);// 4*16*4

  prep_kernel<<<3392, 256, 0, stream>>>(Wm1, Wm2, Wm3, Wg1, Wr, Wt1,
                                        node, prev, edge, graph,
                                        WbT, WgrT, Wm2T, Wm3T, gin);
  gemm_uvt_kernel<<<dim3(64, 18), 64, 0, stream>>>(gin, WbT, uvt);
  maxat_kernel<<<4, 256, 0, stream>>>(uvt, mjk);
  msgmax_kernel<<<1024, 256, 0, stream>>>(uvt, Wm2T, Wm3T, bm1, bm2, bm3, gin);
  gemm_gate_kernel<<<dim3(64, 16), 64, 0, stream>>>(gin, WgrT, bg1, br, r1, hi);
  finalize_kernel<<<1024, 128, 0, stream>>>(r1, hi, prev, uvt, mjk,
                                            Wg2, bg2, bt1, Wt2, bt2, gamma, beta, out);
}

// Round 4
// 71.980 us; speedup vs baseline: 1.0517x; 1.0517x over previous
//
#include <hip/hip_runtime.h>
#include <hip/hip_bf16.h>

typedef unsigned short u16;
typedef unsigned int u32;
typedef float f32x4 __attribute__((ext_vector_type(4)));
typedef short s16x8 __attribute__((ext_vector_type(8)));

#define MFMA16(a,b,c) __builtin_amdgcn_mfma_f32_16x16x32_bf16((a),(b),(c),0,0,0)

static __device__ __forceinline__ u16 f2bf(float x){
  union { __hip_bfloat16 b; u16 u; } c;
  c.b = __float2bfloat16(x);
  return c.u;
}

// ---------------------------------------------------------------------------
// prep: build bf16 transposed/permuted weight buffers + gin[:, 0:512]
// ---------------------------------------------------------------------------
__global__ void prep_kernel(const float* __restrict__ Wm1, const float* __restrict__ Wm2,
                            const float* __restrict__ Wm3, const float* __restrict__ Wg1,
                            const float* __restrict__ Wr,  const float* __restrict__ Wt1,
                            const float* __restrict__ node,const float* __restrict__ prev,
                            const float* __restrict__ edge,const float* __restrict__ graph,
                            u16* __restrict__ WbT, u16* __restrict__ WgrT,
                            u16* __restrict__ Wm2T, u16* __restrict__ Wm3T,
                            u16* __restrict__ gin)
{
  int idx = blockIdx.x * 256 + threadIdx.x;
  if (idx < 147456) {                       // WbT: 288*512
    int n = idx >> 9, k = idx & 511;
    int part = k >> 7, kk = k & 127;
    float v = 0.f;
    if (n < 128) {                          // u = z@W_zi + gb@W_g
      if (part == 0)      v = Wm1[kk*128 + n];
      else if (part == 1) v = Wm1[(128+kk)*128 + n];
      else if (part == 3) v = Wm1[(640+kk)*128 + n];
    } else if (n < 256) {                   // v = z@W_zj + edge@W_e
      int nn = n - 128;
      if (part == 0)      v = Wm1[(256+kk)*128 + nn];
      else if (part == 1) v = Wm1[(384+kk)*128 + nn];
      else if (part == 2) v = Wm1[(512+kk)*128 + nn];
    } else if (n < 280) {                   // a_j(8) a_k(8) c(8)
      int tt = n - 256;
      if (tt < 8)       { if (part == 0) v = Wt1[kk*8 + tt]; }
      else if (tt < 16) { if (part == 0) v = Wt1[(128+kk)*8 + (tt-8)]; }
      else {
        int t = tt - 16;
        if (part == 0)      v = Wt1[(256+kk)*8 + t];
        else if (part == 2) v = Wt1[(384+kk)*8 + t] + Wt1[(512+kk)*8 + t] + Wt1[(640+kk)*8 + t];
        else if (part == 3) v = Wt1[(768+kk)*8 + t];
      }
    }
    WbT[idx] = f2bf(v);
    return;
  }
  idx -= 147456;
  if (idx < 163840) {                       // WgrT: 256*640
    int n = idx / 640, k = idx - n*640;
    int part = k >> 7, kk = k & 127;
    float v = 0.f;
    if (n < 128) {
      int r = (part==0) ? kk : (part==1) ? (128+kk) : (part==2) ? (384+kk)
                        : (part==3) ? (512+kk) : (256+kk);
      v = Wg1[r*128 + n];
    } else {
      int nn = n - 128;
      if (part == 0)      v = Wr[kk*128 + nn];
      else if (part == 1) v = Wr[(128+kk)*128 + nn];
      else if (part == 4) v = Wr[(256+kk)*128 + nn];
    }
    WgrT[idx] = f2bf(v);
    return;
  }
  idx -= 163840;
  if (idx < 16384) { int n = idx >> 7, k = idx & 127; Wm2T[idx] = f2bf(Wm2[k*128 + n]); return; }
  idx -= 16384;
  if (idx < 16384) { int n = idx >> 7, k = idx & 127; Wm3T[idx] = f2bf(Wm3[k*128 + n]); return; }
  idx -= 16384;
  {                                         // gin cols 0:512
    int row = idx >> 9, k = idx & 511;
    int part = k >> 7, kk = k & 127;
    float v;
    if (part == 0)      v = node[row*128 + kk];
    else if (part == 1) v = prev[row*128 + kk];
    else if (part == 2) v = edge[row*128 + kk];
    else                v = graph[(row >> 8)*128 + kk];
    gin[row*640 + k] = f2bf(v);
  }
}

// ---------------------------------------------------------------------------
// G1: uvt[1024][288] = gin[:,0:512] @ WbT^T
// ---------------------------------------------------------------------------
__global__ void gemm_uvt_kernel(const u16* __restrict__ gin, const u16* __restrict__ WbT,
                                float* __restrict__ uvt)
{
  int m0 = blockIdx.x * 16, n0 = blockIdx.y * 16;
  int lane = threadIdx.x;
  int lrow = lane & 15, lgrp = lane >> 4;
  const u16* arow = gin + (size_t)(m0 + lrow) * 640;
  const u16* brow = WbT + (size_t)(n0 + lrow) * 512;
  f32x4 acc = {0.f, 0.f, 0.f, 0.f};
#pragma unroll
  for (int k0 = 0; k0 < 16; ++k0) {
    s16x8 a = *reinterpret_cast<const s16x8*>(arow + k0*32 + lgrp*8);
    s16x8 b = *reinterpret_cast<const s16x8*>(brow + k0*32 + lgrp*8);
    acc = MFMA16(a, b, acc);
  }
#pragma unroll
  for (int r = 0; r < 4; ++r)
    uvt[(size_t)(m0 + lgrp*4 + r) * 288 + n0 + lrow] = acc[r];
}

// ---------------------------------------------------------------------------
// per-batch max over i of a_j, a_k
// ---------------------------------------------------------------------------
__global__ void maxat_kernel(const float* __restrict__ uvt, float* __restrict__ mjk)
{
  int b = blockIdx.x;
  int tid = threadIdx.x;
  int row = b*256 + tid;
  __shared__ float part[4][16];
  float v[16];
#pragma unroll
  for (int t = 0; t < 16; ++t) v[t] = uvt[(size_t)row*288 + 256 + t];
#pragma unroll
  for (int off = 32; off >= 1; off >>= 1) {
#pragma unroll
    for (int t = 0; t < 16; ++t) v[t] = fmaxf(v[t], __shfl_xor(v[t], off));
  }
  int wid = tid >> 6;
  if ((tid & 63) == 0) {
#pragma unroll
    for (int t = 0; t < 16; ++t) part[wid][t] = v[t];
  }
  __syncthreads();
  if (tid < 16)
    mjk[b*16 + tid] = fmaxf(fmaxf(part[0][tid], part[1][tid]),
                            fmaxf(part[2][tid], part[3][tid]));
}

// ---------------------------------------------------------------------------
// msgmax v4: 2 waves/block; wave owns 64 output cols (4 m-tiles, weights in
// registers). a1 is built LANE-LOCAL (lane c,g builds a1[j=c][k-slice g,k0]
// == its own B-fragment) -> a1 never touches LDS, no a1 barrier.
// Only h2 goes through LDS (double-buffered, 1 barrier/iter of 16 j).
// VALU vectorized f32x4 (v_pk_*). NO min-waves launch bound (R3 spill lesson).
// ---------------------------------------------------------------------------
__global__ __launch_bounds__(128) void msgmax_kernel(const float* __restrict__ uvt,
    const u16* __restrict__ Wm2T, const u16* __restrict__ Wm3T,
    const float* __restrict__ bm1, const float* __restrict__ bm2,
    const float* __restrict__ bm3, u16* __restrict__ gin)
{
  const int row = blockIdx.x;
  const int b   = row >> 8;
  const int tid = threadIdx.x;
  const int w   = tid >> 6;          // 0..1: col-half
  const int lane = tid & 63;
  const int c = lane & 15, g = lane >> 4;

  __shared__ u16 h2s[2][4][16][40];  // [buf][k-chunk][j(c)][32 used + 8 pad]

  // persistent weight A-fragments (swapped GEMM): 4 m-tiles per wave
  s16x8 wb2[4][4], wb3[4][4];        // [k0][mt]
#pragma unroll
  for (int mt = 0; mt < 4; ++mt) {
    int col = w*64 + mt*16 + c;
#pragma unroll
    for (int k0 = 0; k0 < 4; ++k0) {
      wb2[k0][mt] = *reinterpret_cast<const s16x8*>(Wm2T + col*128 + k0*32 + g*8);
      wb3[k0][mt] = *reinterpret_cast<const s16x8*>(Wm3T + col*128 + k0*32 + g*8);
    }
  }
  f32x4 bm2v[4];
#pragma unroll
  for (int mt = 0; mt < 4; ++mt)
    bm2v[mt] = *reinterpret_cast<const f32x4*>(bm2 + w*64 + mt*16 + 4*g);

  // u (+bm1): full 128-k lane slice: k = k0*32 + g*8 + 0..7
  f32x4 uf[4][2];
  {
    const float* urow = uvt + (size_t)row * 288;
#pragma unroll
    for (int k0 = 0; k0 < 4; ++k0) {
      int off = k0*32 + g*8;
      uf[k0][0] = *reinterpret_cast<const f32x4*>(urow + off)
                + *reinterpret_cast<const f32x4*>(bm1 + off);
      uf[k0][1] = *reinterpret_cast<const f32x4*>(urow + off + 4)
                + *reinterpret_cast<const f32x4*>(bm1 + off + 4);
    }
  }

  const float* vb = uvt + (size_t)(b*256) * 288 + 128;
  const f32x4 z4 = {0.f, 0.f, 0.f, 0.f};
  f32x4 mmax[4];
#pragma unroll
  for (int mt = 0; mt < 4; ++mt) mmax[mt] = {-1e30f, -1e30f, -1e30f, -1e30f};

  for (int jt = 0; jt < 16; ++jt) {
    // ---- build lane-local a1 B-frags: a1[j=c][k0*32+g*8..+8] ----
    const float* vrow = vb + (size_t)(jt*16 + c) * 288 + g*8;
    s16x8 a1f[4];
#pragma unroll
    for (int k0 = 0; k0 < 4; ++k0) {
      f32x4 lo = __builtin_elementwise_max(
                   *reinterpret_cast<const f32x4*>(vrow + k0*32) + uf[k0][0], z4);
      f32x4 hi = __builtin_elementwise_max(
                   *reinterpret_cast<const f32x4*>(vrow + k0*32 + 4) + uf[k0][1], z4);
      s16x8 f;
      f[0] = (short)f2bf(lo[0]); f[1] = (short)f2bf(lo[1]);
      f[2] = (short)f2bf(lo[2]); f[3] = (short)f2bf(lo[3]);
      f[4] = (short)f2bf(hi[0]); f[5] = (short)f2bf(hi[1]);
      f[6] = (short)f2bf(hi[2]); f[7] = (short)f2bf(hi[3]);
      a1f[k0] = f;
    }

    // ---- GEMM1 (no LDS reads): acc1[mt] over k0 ----
    f32x4 acc1[4] = {z4, z4, z4, z4};
#pragma unroll
    for (int k0 = 0; k0 < 4; ++k0) {
#pragma unroll
      for (int mt = 0; mt < 4; ++mt)
        acc1[mt] = MFMA16(wb2[k0][mt], a1f[k0], acc1[mt]);
    }

    // ---- h2 = relu(acc1+bm2) -> LDS (by k-chunk for GEMM2 reads) ----
    int buf = jt & 1;
#pragma unroll
    for (int mt = 0; mt < 4; ++mt) {
      f32x4 t = __builtin_elementwise_max(acc1[mt] + bm2v[mt], z4);
      u32 lo = (u32)f2bf(t[0]) | ((u32)f2bf(t[1]) << 16);
      u32 hi = (u32)f2bf(t[2]) | ((u32)f2bf(t[3]) << 16);
      uint2 pk = {lo, hi};
      *reinterpret_cast<uint2*>(&h2s[buf][w*2 + (mt>>1)][c][(mt&1)*16 + 4*g]) = pk;
    }
    __syncthreads();

    // ---- GEMM2: read full-k h2 frags, accumulate, fold max ----
    f32x4 acc2[4] = {z4, z4, z4, z4};
#pragma unroll
    for (int k0 = 0; k0 < 4; ++k0) {
      s16x8 a2 = *reinterpret_cast<const s16x8*>(&h2s[buf][k0][c][g*8]);
#pragma unroll
      for (int mt = 0; mt < 4; ++mt)
        acc2[mt] = MFMA16(wb3[k0][mt], a2, acc2[mt]);
    }
#pragma unroll
    for (int mt = 0; mt < 4; ++mt)
      mmax[mt] = __builtin_elementwise_max(mmax[mt], acc2[mt]);
  }

  // reduce over the 16 j-lanes (c bits), fold bm3, packed global write
#pragma unroll
  for (int mt = 0; mt < 4; ++mt) {
    f32x4 m = mmax[mt];
#pragma unroll
    for (int off = 1; off < 16; off <<= 1) {
      m[0] = fmaxf(m[0], __shfl_xor(m[0], off));
      m[1] = fmaxf(m[1], __shfl_xor(m[1], off));
      m[2] = fmaxf(m[2], __shfl_xor(m[2], off));
      m[3] = fmaxf(m[3], __shfl_xor(m[3], off));
    }
    if (c == 0) {
      int col = w*64 + mt*16 + 4*g;
      u32 lo = (u32)f2bf(m[0] + bm3[col])   | ((u32)f2bf(m[1] + bm3[col+1]) << 16);
      u32 hi = (u32)f2bf(m[2] + bm3[col+2]) | ((u32)f2bf(m[3] + bm3[col+3]) << 16);
      uint2 pk = {lo, hi};
      *reinterpret_cast<uint2*>(gin + (size_t)row*640 + 512 + col) = pk;
    }
  }
}

// ---------------------------------------------------------------------------
// G2: [r1 | h_i] = gin(K=640) @ WgrT^T
// ---------------------------------------------------------------------------
__global__ void gemm_gate_kernel(const u16* __restrict__ gin, const u16* __restrict__ WgrT,
                                 const float* __restrict__ bg1, const float* __restrict__ br,
                                 float* __restrict__ r1, float* __restrict__ hi)
{
  int m0 = blockIdx.x * 16, n0 = blockIdx.y * 16;
  int lane = threadIdx.x;
  int lrow = lane & 15, lgrp = lane >> 4;
  const u16* arow = gin  + (size_t)(m0 + lrow) * 640;
  const u16* brow = WgrT + (size_t)(n0 + lrow) * 640;
  f32x4 acc = {0.f, 0.f, 0.f, 0.f};
#pragma unroll
  for (int k0 = 0; k0 < 20; ++k0) {
    s16x8 a = *reinterpret_cast<const s16x8*>(arow + k0*32 + lgrp*8);
    s16x8 b = *reinterpret_cast<const s16x8*>(brow + k0*32 + lgrp*8);
    acc = MFMA16(a, b, acc);
  }
  int col = n0 + lrow;
  float bv = (col < 128) ? bg1[col] : br[col - 128];
#pragma unroll
  for (int r = 0; r < 4; ++r) {
    int gr = m0 + lgrp*4 + r;
    if (col < 128) r1[gr*128 + col] = fmaxf(acc[r] + bv, 0.f);
    else           hi[gr*128 + col - 128] = acc[r] + bv;
  }
}

// ---------------------------------------------------------------------------
// finalize
// ---------------------------------------------------------------------------
__global__ void finalize_kernel(const float* __restrict__ r1, const float* __restrict__ hi,
                                const float* __restrict__ prev, const float* __restrict__ uvt,
                                const float* __restrict__ mjk,
                                const float* __restrict__ Wg2, const float* __restrict__ bg2,
                                const float* __restrict__ bt1, const float* __restrict__ Wt2,
                                const float* __restrict__ bt2, const float* __restrict__ gamma,
                                const float* __restrict__ beta, float* __restrict__ out)
{
  int row = blockIdx.x;
  int h = threadIdx.x;
  int b = row >> 8;
  __shared__ float r1s[128];
  __shared__ float red[4];
  r1s[h] = r1[row*128 + h];
  __syncthreads();
  float glin = bg2[h];
#pragma unroll 8
  for (int k = 0; k < 128; ++k) glin += r1s[k] * Wg2[k*128 + h];
  float g = 1.f / (1.f + __expf(-glin));
  float hg = g * hi[row*128 + h] + (1.f - g) * prev[row*128 + h];

  float s1 = hg, s2 = hg*hg;
#pragma unroll
  for (int off = 1; off < 64; off <<= 1) {
    s1 += __shfl_xor(s1, off);
    s2 += __shfl_xor(s2, off);
  }
  int wid = h >> 6;
  if ((h & 63) == 0) { red[wid] = s1; red[2 + wid] = s2; }
  __syncthreads();
  float mu  = (red[0] + red[1]) * 0.0078125f;
  float ex2 = (red[2] + red[3]) * 0.0078125f;
  float var = ex2 - mu*mu;
  float hn = (hg - mu) * rsqrtf(var + 1e-5f) * gamma[h] + beta[h];
  out[row*128 + h] = hn;

  float o2 = bt2[h];
#pragma unroll
  for (int t = 0; t < 8; ++t) {
    float tv = uvt[(size_t)row*288 + 272 + t] + bt1[t] + mjk[b*16 + t] + mjk[b*16 + 8 + t];
    tv = fmaxf(tv, 0.f);
    o2 += tv * Wt2[t*128 + h];
  }
  out[131072 + row*128 + h] = o2;
}

// ---------------------------------------------------------------------------
extern "C" void kernel_launch(void* const* d_in, const int* in_sizes, int n_in,
                              void* d_out, int out_size, void* d_ws, size_t ws_size,
                              hipStream_t stream) {
  const float* node  = (const float*)d_in[0];
  const float* edge  = (const float*)d_in[1];
  const float* graph = (const float*)d_in[2];
  const float* prev  = (const float*)d_in[3];
  const float* Wm1 = (const float*)d_in[4];
  const float* bm1 = (const float*)d_in[5];
  const float* Wm2 = (const float*)d_in[6];
  const float* bm2 = (const float*)d_in[7];
  const float* Wm3 = (const float*)d_in[8];
  const float* bm3 = (const float*)d_in[9];
  const float* Wg1 = (const float*)d_in[10];
  const float* bg1 = (const float*)d_in[11];
  const float* Wg2 = (const float*)d_in[12];
  const float* bg2 = (const float*)d_in[13];
  const float* Wr  = (const float*)d_in[14];
  const float* br  = (const float*)d_in[15];
  const float* Wt1 = (const float*)d_in[16];
  const float* bt1 = (const float*)d_in[17];
  const float* Wt2 = (const float*)d_in[18];
  const float* bt2 = (const float*)d_in[19];
  const float* gamma = (const float*)d_in[20];
  const float* beta  = (const float*)d_in[21];
  float* out = (float*)d_out;

  char* ws = (char*)d_ws;
  u16*   WbT  = (u16*)(ws + 0);        // 288*512*2   = 294912
  u16*   WgrT = (u16*)(ws + 294912);   // 256*640*2   = 327680
  u16*   Wm2T = (u16*)(ws + 622592);   // 16384*2
  u16*   Wm3T = (u16*)(ws + 655360);   // 16384*2
  u16*   gin  = (u16*)(ws + 688128);   // 1024*640*2  = 1310720
  float* uvt  = (float*)(ws + 1998848);// 1024*288*4  = 1179648
  float* r1   = (float*)(ws + 3178496);// 1024*128*4  = 524288
  float* hi   = (float*)(ws + 3702784);// 524288
  float* mjk  = (float*)(ws + 4227072);// 4*16*4

  prep_kernel<<<3392, 256, 0, stream>>>(Wm1, Wm2, Wm3, Wg1, Wr, Wt1,
                                        node, prev, edge, graph,
                                        WbT, WgrT, Wm2T, Wm3T, gin);
  gemm_uvt_kernel<<<dim3(64, 18), 64, 0, stream>>>(gin, WbT, uvt);
  maxat_kernel<<<4, 256, 0, stream>>>(uvt, mjk);
  msgmax_kernel<<<1024, 128, 0, stream>>>(uvt, Wm2T, Wm3T, bm1, bm2, bm3, gin);
  gemm_gate_kernel<<<dim3(64, 16), 64, 0, stream>>>(gin, WgrT, bg1, br, r1, hi);
  finalize_kernel<<<1024, 128, 0, stream>>>(r1, hi, prev, uvt, mjk,
                                            Wg2, bg2, bt1, Wt2, bt2, gamma, beta, out);
}

// Round 5
// 60.523 us; speedup vs baseline: 1.2508x; 1.1893x over previous
//
#include <hip/hip_runtime.h>
#include <hip/hip_bf16.h>

typedef unsigned short u16;
typedef unsigned int u32;
typedef float f32x4 __attribute__((ext_vector_type(4)));
typedef short s16x8 __attribute__((ext_vector_type(8)));

#define MFMA16(a,b,c) __builtin_amdgcn_mfma_f32_16x16x32_bf16((a),(b),(c),0,0,0)

static __device__ __forceinline__ u16 f2bf(float x){
  union { __hip_bfloat16 b; u16 u; } c;
  c.b = __float2bfloat16(x);
  return c.u;
}

// ---------------------------------------------------------------------------
// prep: build bf16 transposed/permuted weight buffers + gin[:, 0:512]
// ---------------------------------------------------------------------------
__global__ void prep_kernel(const float* __restrict__ Wm1, const float* __restrict__ Wm2,
                            const float* __restrict__ Wm3, const float* __restrict__ Wg1,
                            const float* __restrict__ Wr,  const float* __restrict__ Wt1,
                            const float* __restrict__ node,const float* __restrict__ prev,
                            const float* __restrict__ edge,const float* __restrict__ graph,
                            u16* __restrict__ WbT, u16* __restrict__ WgrT,
                            u16* __restrict__ Wm2T, u16* __restrict__ Wm3T,
                            u16* __restrict__ gin)
{
  int idx = blockIdx.x * 256 + threadIdx.x;
  if (idx < 147456) {                       // WbT: 288*512
    int n = idx >> 9, k = idx & 511;
    int part = k >> 7, kk = k & 127;
    float v = 0.f;
    if (n < 128) {                          // u = z@W_zi + gb@W_g
      if (part == 0)      v = Wm1[kk*128 + n];
      else if (part == 1) v = Wm1[(128+kk)*128 + n];
      else if (part == 3) v = Wm1[(640+kk)*128 + n];
    } else if (n < 256) {                   // v = z@W_zj + edge@W_e
      int nn = n - 128;
      if (part == 0)      v = Wm1[(256+kk)*128 + nn];
      else if (part == 1) v = Wm1[(384+kk)*128 + nn];
      else if (part == 2) v = Wm1[(512+kk)*128 + nn];
    } else if (n < 280) {                   // a_j(8) a_k(8) c(8)
      int tt = n - 256;
      if (tt < 8)       { if (part == 0) v = Wt1[kk*8 + tt]; }
      else if (tt < 16) { if (part == 0) v = Wt1[(128+kk)*8 + (tt-8)]; }
      else {
        int t = tt - 16;
        if (part == 0)      v = Wt1[(256+kk)*8 + t];
        else if (part == 2) v = Wt1[(384+kk)*8 + t] + Wt1[(512+kk)*8 + t] + Wt1[(640+kk)*8 + t];
        else if (part == 3) v = Wt1[(768+kk)*8 + t];
      }
    }
    WbT[idx] = f2bf(v);
    return;
  }
  idx -= 147456;
  if (idx < 163840) {                       // WgrT: 256*640
    int n = idx / 640, k = idx - n*640;
    int part = k >> 7, kk = k & 127;
    float v = 0.f;
    if (n < 128) {
      int r = (part==0) ? kk : (part==1) ? (128+kk) : (part==2) ? (384+kk)
                        : (part==3) ? (512+kk) : (256+kk);
      v = Wg1[r*128 + n];
    } else {
      int nn = n - 128;
      if (part == 0)      v = Wr[kk*128 + nn];
      else if (part == 1) v = Wr[(128+kk)*128 + nn];
      else if (part == 4) v = Wr[(256+kk)*128 + nn];
    }
    WgrT[idx] = f2bf(v);
    return;
  }
  idx -= 163840;
  if (idx < 16384) { int n = idx >> 7, k = idx & 127; Wm2T[idx] = f2bf(Wm2[k*128 + n]); return; }
  idx -= 16384;
  if (idx < 16384) { int n = idx >> 7, k = idx & 127; Wm3T[idx] = f2bf(Wm3[k*128 + n]); return; }
  idx -= 16384;
  {                                         // gin cols 0:512
    int row = idx >> 9, k = idx & 511;
    int part = k >> 7, kk = k & 127;
    float v;
    if (part == 0)      v = node[row*128 + kk];
    else if (part == 1) v = prev[row*128 + kk];
    else if (part == 2) v = edge[row*128 + kk];
    else                v = graph[(row >> 8)*128 + kk];
    gin[row*640 + k] = f2bf(v);
  }
}

// ---------------------------------------------------------------------------
// G1: uvt[1024][288] = gin[:,0:512] @ WbT^T
// ---------------------------------------------------------------------------
__global__ void gemm_uvt_kernel(const u16* __restrict__ gin, const u16* __restrict__ WbT,
                                float* __restrict__ uvt)
{
  int m0 = blockIdx.x * 16, n0 = blockIdx.y * 16;
  int lane = threadIdx.x;
  int lrow = lane & 15, lgrp = lane >> 4;
  const u16* arow = gin + (size_t)(m0 + lrow) * 640;
  const u16* brow = WbT + (size_t)(n0 + lrow) * 512;
  f32x4 acc = {0.f, 0.f, 0.f, 0.f};
#pragma unroll
  for (int k0 = 0; k0 < 16; ++k0) {
    s16x8 a = *reinterpret_cast<const s16x8*>(arow + k0*32 + lgrp*8);
    s16x8 b = *reinterpret_cast<const s16x8*>(brow + k0*32 + lgrp*8);
    acc = MFMA16(a, b, acc);
  }
#pragma unroll
  for (int r = 0; r < 4; ++r)
    uvt[(size_t)(m0 + lgrp*4 + r) * 288 + n0 + lrow] = acc[r];
}

// ---------------------------------------------------------------------------
// per-batch max over i of a_j, a_k
// ---------------------------------------------------------------------------
__global__ void maxat_kernel(const float* __restrict__ uvt, float* __restrict__ mjk)
{
  int b = blockIdx.x;
  int tid = threadIdx.x;
  int row = b*256 + tid;
  __shared__ float part[4][16];
  float v[16];
#pragma unroll
  for (int t = 0; t < 16; ++t) v[t] = uvt[(size_t)row*288 + 256 + t];
#pragma unroll
  for (int off = 32; off >= 1; off >>= 1) {
#pragma unroll
    for (int t = 0; t < 16; ++t) v[t] = fmaxf(v[t], __shfl_xor(v[t], off));
  }
  int wid = tid >> 6;
  if ((tid & 63) == 0) {
#pragma unroll
    for (int t = 0; t < 16; ++t) part[wid][t] = v[t];
  }
  __syncthreads();
  if (tid < 16)
    mjk[b*16 + tid] = fmaxf(fmaxf(part[0][tid], part[1][tid]),
                            fmaxf(part[2][tid], part[3][tid]));
}

// ---------------------------------------------------------------------------
// msgmax v5: exact v2 structure (measured 35us) with ONE change: a1s rows
// padded 32->40 u16 (20-dword c-stride) so the GEMM1 b128 reads/writes go
// 8-way -> 2-way bank aliasing (free). Block = one (b,i), 4 waves,
// j streamed 32/iter, a1 k-slices shared via LDS, v prefetched.
// ---------------------------------------------------------------------------
__global__ __launch_bounds__(256) void msgmax_kernel(const float* __restrict__ uvt,
    const u16* __restrict__ Wm2T, const u16* __restrict__ Wm3T,
    const float* __restrict__ bm1, const float* __restrict__ bm2,
    const float* __restrict__ bm3, u16* __restrict__ gin)
{
  const int row = blockIdx.x;
  const int b   = row >> 8;
  const int tid = threadIdx.x;
  const int w   = tid >> 6;
  const int lane = tid & 63;
  const int c = lane & 15, g = lane >> 4;

  __shared__ u16 a1s[2][4][16][40];   // [j-half][k0][j(c)][32 used + 8 pad]
  __shared__ u16 h2s[2][16][136];     // [j-half][j(c)][128 + 8 pad]

  // persistent weight A-fragments (swapped GEMM): rows = output cols
  s16x8 wb2[4][2], wb3[4][2];
#pragma unroll
  for (int mt = 0; mt < 2; ++mt) {
    int col = w*32 + mt*16 + c;
#pragma unroll
    for (int k0 = 0; k0 < 4; ++k0) {
      wb2[k0][mt] = *reinterpret_cast<const s16x8*>(Wm2T + col*128 + k0*32 + g*8);
      wb3[k0][mt] = *reinterpret_cast<const s16x8*>(Wm3T + col*128 + k0*32 + g*8);
    }
  }
  float4 bm2v[2];
#pragma unroll
  for (int mt = 0; mt < 2; ++mt)
    bm2v[mt] = *reinterpret_cast<const float4*>(bm2 + w*32 + mt*16 + 4*g);

  // u slice (k0 == w only), +bm1
  const float* urow = uvt + (size_t)row * 288;
  float uf[8];
  {
    int off = w*32 + g*8;
    float4 x = *reinterpret_cast<const float4*>(urow + off);
    float4 y = *reinterpret_cast<const float4*>(urow + off + 4);
    float4 p = *reinterpret_cast<const float4*>(bm1 + off);
    float4 q = *reinterpret_cast<const float4*>(bm1 + off + 4);
    uf[0]=x.x+p.x; uf[1]=x.y+p.y; uf[2]=x.z+p.z; uf[3]=x.w+p.w;
    uf[4]=y.x+q.x; uf[5]=y.y+q.y; uf[6]=y.z+q.z; uf[7]=y.w+q.w;
  }

  const float* vb = uvt + (size_t)(b*256) * 288 + 128;
  f32x4 mmax[2];
#pragma unroll
  for (int mt = 0; mt < 2; ++mt)
#pragma unroll
    for (int r = 0; r < 4; ++r) mmax[mt][r] = -1e30f;

  float4 vc[2][2];   // v slices for the next j-block: [jhalf][lo/hi]
#define LOADV(IT) do { \
  _Pragma("unroll") \
  for (int t = 0; t < 2; ++t) { \
    const float* p_ = vb + (size_t)((IT)*32 + t*16 + c) * 288 + w*32 + g*8; \
    vc[t][0] = *reinterpret_cast<const float4*>(p_); \
    vc[t][1] = *reinterpret_cast<const float4*>(p_ + 4); } } while (0)

  LOADV(0);

  for (int it = 0; it < 8; ++it) {
    // build own a1 slice (k0 == w) for both j-tiles, packed b128 write
#pragma unroll
    for (int t = 0; t < 2; ++t) {
      u32 d0 = (u32)f2bf(fmaxf(uf[0] + vc[t][0].x, 0.f))
             | ((u32)f2bf(fmaxf(uf[1] + vc[t][0].y, 0.f)) << 16);
      u32 d1 = (u32)f2bf(fmaxf(uf[2] + vc[t][0].z, 0.f))
             | ((u32)f2bf(fmaxf(uf[3] + vc[t][0].w, 0.f)) << 16);
      u32 d2 = (u32)f2bf(fmaxf(uf[4] + vc[t][1].x, 0.f))
             | ((u32)f2bf(fmaxf(uf[5] + vc[t][1].y, 0.f)) << 16);
      u32 d3 = (u32)f2bf(fmaxf(uf[6] + vc[t][1].z, 0.f))
             | ((u32)f2bf(fmaxf(uf[7] + vc[t][1].w, 0.f)) << 16);
      uint4 pk = {d0, d1, d2, d3};
      *reinterpret_cast<uint4*>(&a1s[t][w][c][g*8]) = pk;
    }
    if (it < 7) LOADV(it + 1);          // prefetch next v under this iter's compute
    __syncthreads();                    // a1 ready

    // GEMM1 (swapped): h2^T tiles
    f32x4 acc1[2][2] = {{{0,0,0,0},{0,0,0,0}},{{0,0,0,0},{0,0,0,0}}};
#pragma unroll
    for (int t = 0; t < 2; ++t)
#pragma unroll
      for (int k0 = 0; k0 < 4; ++k0) {
        s16x8 af = *reinterpret_cast<const s16x8*>(&a1s[t][k0][c][g*8]);
        acc1[t][0] = MFMA16(wb2[k0][0], af, acc1[t][0]);
        acc1[t][1] = MFMA16(wb2[k0][1], af, acc1[t][1]);
      }

    // h2 = relu(acc1 + bm2) -> packed b64 writes (lane holds 4 consecutive h)
#pragma unroll
    for (int t = 0; t < 2; ++t)
#pragma unroll
      for (int mt = 0; mt < 2; ++mt) {
        u32 lo = (u32)f2bf(fmaxf(acc1[t][mt][0] + bm2v[mt].x, 0.f))
               | ((u32)f2bf(fmaxf(acc1[t][mt][1] + bm2v[mt].y, 0.f)) << 16);
        u32 hi = (u32)f2bf(fmaxf(acc1[t][mt][2] + bm2v[mt].z, 0.f))
               | ((u32)f2bf(fmaxf(acc1[t][mt][3] + bm2v[mt].w, 0.f)) << 16);
        uint2 pk = {lo, hi};
        *reinterpret_cast<uint2*>(&h2s[t][c][w*32 + mt*16 + 4*g]) = pk;
      }
    __syncthreads();                    // h2 ready

    // GEMM2 (swapped): msgs^T tiles, then running max over j
    f32x4 acc2[2][2] = {{{0,0,0,0},{0,0,0,0}},{{0,0,0,0},{0,0,0,0}}};
#pragma unroll
    for (int t = 0; t < 2; ++t)
#pragma unroll
      for (int k0 = 0; k0 < 4; ++k0) {
        s16x8 a2 = *reinterpret_cast<const s16x8*>(&h2s[t][c][k0*32 + g*8]);
        acc2[t][0] = MFMA16(wb3[k0][0], a2, acc2[t][0]);
        acc2[t][1] = MFMA16(wb3[k0][1], a2, acc2[t][1]);
      }
#pragma unroll
    for (int mt = 0; mt < 2; ++mt)
#pragma unroll
      for (int r = 0; r < 4; ++r)
        mmax[mt][r] = fmaxf(mmax[mt][r], fmaxf(acc2[0][mt][r], acc2[1][mt][r]));
  }
#undef LOADV

  // reduce over the 16 j-lanes (c bits), fold bm3, packed global write
#pragma unroll
  for (int mt = 0; mt < 2; ++mt) {
    f32x4 m = mmax[mt];
#pragma unroll
    for (int off = 1; off < 16; off <<= 1) {
      m[0] = fmaxf(m[0], __shfl_xor(m[0], off));
      m[1] = fmaxf(m[1], __shfl_xor(m[1], off));
      m[2] = fmaxf(m[2], __shfl_xor(m[2], off));
      m[3] = fmaxf(m[3], __shfl_xor(m[3], off));
    }
    if (c == 0) {
      int col = w*32 + mt*16 + 4*g;
      u32 lo = (u32)f2bf(m[0] + bm3[col])   | ((u32)f2bf(m[1] + bm3[col+1]) << 16);
      u32 hi = (u32)f2bf(m[2] + bm3[col+2]) | ((u32)f2bf(m[3] + bm3[col+3]) << 16);
      uint2 pk = {lo, hi};
      *reinterpret_cast<uint2*>(gin + (size_t)row*640 + 512 + col) = pk;
    }
  }
}

// ---------------------------------------------------------------------------
// G2: [r1 | h_i] = gin(K=640) @ WgrT^T
// ---------------------------------------------------------------------------
__global__ void gemm_gate_kernel(const u16* __restrict__ gin, const u16* __restrict__ WgrT,
                                 const float* __restrict__ bg1, const float* __restrict__ br,
                                 float* __restrict__ r1, float* __restrict__ hi)
{
  int m0 = blockIdx.x * 16, n0 = blockIdx.y * 16;
  int lane = threadIdx.x;
  int lrow = lane & 15, lgrp = lane >> 4;
  const u16* arow = gin  + (size_t)(m0 + lrow) * 640;
  const u16* brow = WgrT + (size_t)(n0 + lrow) * 640;
  f32x4 acc = {0.f, 0.f, 0.f, 0.f};
#pragma unroll
  for (int k0 = 0; k0 < 20; ++k0) {
    s16x8 a = *reinterpret_cast<const s16x8*>(arow + k0*32 + lgrp*8);
    s16x8 b = *reinterpret_cast<const s16x8*>(brow + k0*32 + lgrp*8);
    acc = MFMA16(a, b, acc);
  }
  int col = n0 + lrow;
  float bv = (col < 128) ? bg1[col] : br[col - 128];
#pragma unroll
  for (int r = 0; r < 4; ++r) {
    int gr = m0 + lgrp*4 + r;
    if (col < 128) r1[gr*128 + col] = fmaxf(acc[r] + bv, 0.f);
    else           hi[gr*128 + col - 128] = acc[r] + bv;
  }
}

// ---------------------------------------------------------------------------
// finalize
// ---------------------------------------------------------------------------
__global__ void finalize_kernel(const float* __restrict__ r1, const float* __restrict__ hi,
                                const float* __restrict__ prev, const float* __restrict__ uvt,
                                const float* __restrict__ mjk,
                                const float* __restrict__ Wg2, const float* __restrict__ bg2,
                                const float* __restrict__ bt1, const float* __restrict__ Wt2,
                                const float* __restrict__ bt2, const float* __restrict__ gamma,
                                const float* __restrict__ beta, float* __restrict__ out)
{
  int row = blockIdx.x;
  int h = threadIdx.x;
  int b = row >> 8;
  __shared__ float r1s[128];
  __shared__ float red[4];
  r1s[h] = r1[row*128 + h];
  __syncthreads();
  float glin = bg2[h];
#pragma unroll 8
  for (int k = 0; k < 128; ++k) glin += r1s[k] * Wg2[k*128 + h];
  float g = 1.f / (1.f + __expf(-glin));
  float hg = g * hi[row*128 + h] + (1.f - g) * prev[row*128 + h];

  float s1 = hg, s2 = hg*hg;
#pragma unroll
  for (int off = 1; off < 64; off <<= 1) {
    s1 += __shfl_xor(s1, off);
    s2 += __shfl_xor(s2, off);
  }
  int wid = h >> 6;
  if ((h & 63) == 0) { red[wid] = s1; red[2 + wid] = s2; }
  __syncthreads();
  float mu  = (red[0] + red[1]) * 0.0078125f;
  float ex2 = (red[2] + red[3]) * 0.0078125f;
  float var = ex2 - mu*mu;
  float hn = (hg - mu) * rsqrtf(var + 1e-5f) * gamma[h] + beta[h];
  out[row*128 + h] = hn;

  float o2 = bt2[h];
#pragma unroll
  for (int t = 0; t < 8; ++t) {
    float tv = uvt[(size_t)row*288 + 272 + t] + bt1[t] + mjk[b*16 + t] + mjk[b*16 + 8 + t];
    tv = fmaxf(tv, 0.f);
    o2 += tv * Wt2[t*128 + h];
  }
  out[131072 + row*128 + h] = o2;
}

// ---------------------------------------------------------------------------
extern "C" void kernel_launch(void* const* d_in, const int* in_sizes, int n_in,
                              void* d_out, int out_size, void* d_ws, size_t ws_size,
                              hipStream_t stream) {
  const float* node  = (const float*)d_in[0];
  const float* edge  = (const float*)d_in[1];
  const float* graph = (const float*)d_in[2];
  const float* prev  = (const float*)d_in[3];
  const float* Wm1 = (const float*)d_in[4];
  const float* bm1 = (const float*)d_in[5];
  const float* Wm2 = (const float*)d_in[6];
  const float* bm2 = (const float*)d_in[7];
  const float* Wm3 = (const float*)d_in[8];
  const float* bm3 = (const float*)d_in[9];
  const float* Wg1 = (const float*)d_in[10];
  const float* bg1 = (const float*)d_in[11];
  const float* Wg2 = (const float*)d_in[12];
  const float* bg2 = (const float*)d_in[13];
  const float* Wr  = (const float*)d_in[14];
  const float* br  = (const float*)d_in[15];
  const float* Wt1 = (const float*)d_in[16];
  const float* bt1 = (const float*)d_in[17];
  const float* Wt2 = (const float*)d_in[18];
  const float* bt2 = (const float*)d_in[19];
  const float* gamma = (const float*)d_in[20];
  const float* beta  = (const float*)d_in[21];
  float* out = (float*)d_out;

  char* ws = (char*)d_ws;
  u16*   WbT  = (u16*)(ws + 0);        // 288*512*2   = 294912
  u16*   WgrT = (u16*)(ws + 294912);   // 256*640*2   = 327680
  u16*   Wm2T = (u16*)(ws + 622592);   // 16384*2
  u16*   Wm3T = (u16*)(ws + 655360);   // 16384*2
  u16*   gin  = (u16*)(ws + 688128);   // 1024*640*2  = 1310720
  float* uvt  = (float*)(ws + 1998848);// 1024*288*4  = 1179648
  float* r1   = (float*)(ws + 3178496);// 1024*128*4  = 524288
  float* hi   = (float*)(ws + 3702784);// 524288
  float* mjk  = (float*)(ws + 4227072);// 4*16*4

  prep_kernel<<<3392, 256, 0, stream>>>(Wm1, Wm2, Wm3, Wg1, Wr, Wt1,
                                        node, prev, edge, graph,
                                        WbT, WgrT, Wm2T, Wm3T, gin);
  gemm_uvt_kernel<<<dim3(64, 18), 64, 0, stream>>>(gin, WbT, uvt);
  maxat_kernel<<<4, 256, 0, stream>>>(uvt, mjk);
  msgmax_kernel<<<1024, 256, 0, stream>>>(uvt, Wm2T, Wm3T, bm1, bm2, bm3, gin);
  gemm_gate_kernel<<<dim3(64, 16), 64, 0, stream>>>(gin, WgrT, bg1, br, r1, hi);
  finalize_kernel<<<1024, 128, 0, stream>>>(r1, hi, prev, uvt, mjk,
                                            Wg2, bg2, bt1, Wt2, bt2, gamma, beta, out);
}